// Round 11
// baseline (296.743 us; speedup 1.0000x reference)
//
#include <hip/hip_runtime.h>

#define EPS_DIST 1e-10f
#define BN_EPS 1e-5f

typedef short short8 __attribute__((ext_vector_type(8)));
typedef float floatx4 __attribute__((ext_vector_type(4)));

__device__ __forceinline__ unsigned short f2bf(float f) {
  unsigned u = __float_as_uint(f);
  unsigned r = (u + 0x7FFFu + ((u >> 16) & 1u)) >> 16;  // RNE
  return (unsigned short)r;
}
__device__ __forceinline__ float bf2f(unsigned short h) {
  return __uint_as_float(((unsigned)h) << 16);
}

// ---------------- kernel 1: 3-NN + weights, 8 lanes per query ----------------
// grid (128 qtile, 16 b), block 256 (32 queries x 8 lanes)
__global__ __launch_bounds__(256) void knn_kernel(
    const float* __restrict__ xyz1, const float* __restrict__ xyz2,
    int* __restrict__ idxo, float* __restrict__ wo) {
  __shared__ float4 s2[1024];  // x,y,z,|.|^2
  const int b = blockIdx.y;
  const int tid = threadIdx.x;
  const float* x2 = xyz2 + b * 3072;
  for (int j = tid; j < 1024; j += 256) {
    float x = x2[j * 3 + 0], y = x2[j * 3 + 1], z = x2[j * 3 + 2];
    s2[j] = make_float4(x, y, z, (x * x + y * y) + z * z);
  }
  __syncthreads();
  const int q = tid >> 3, sub = tid & 7;
  const int n = blockIdx.x * 32 + q;
  const float* p1 = xyz1 + (b * 4096 + n) * 3;
  const float ax = p1[0], ay = p1[1], az = p1[2];
  const float s1 = (ax * ax + ay * ay) + az * az;
  float d0 = 3.4e38f, d1 = 3.4e38f, d2 = 3.4e38f;
  int i0 = 0x7fffffff, i1 = 0x7fffffff, i2 = 0x7fffffff;
  for (int jj = 0; jj < 128; ++jj) {
    int j = jj * 8 + sub;
    float4 c = s2[j];
    float dot = (ax * c.x + ay * c.y) + az * c.z;
    float d = (s1 + c.w) - 2.0f * dot;
    d = fmaxf(d, EPS_DIST);
    if (d < d2) {
      if (d < d1) {
        d2 = d1; i2 = i1;
        if (d < d0) { d1 = d0; i1 = i0; d0 = d; i0 = j; }
        else { d1 = d; i1 = j; }
      } else { d2 = d; i2 = j; }
    }
  }
  // butterfly merge of sorted (d,idx) triples; lexicographic == lax.top_k order
#pragma unroll
  for (int m = 1; m <= 4; m <<= 1) {
    float e0 = __shfl_xor(d0, m), e1 = __shfl_xor(d1, m), e2 = __shfl_xor(d2, m);
    int   f0 = __shfl_xor(i0, m), f1 = __shfl_xor(i1, m), f2 = __shfl_xor(i2, m);
    float A[3] = {d0, d1, d2}, Bv[3] = {e0, e1, e2};
    int   I[3] = {i0, i1, i2}, J[3] = {f0, f1, f2};
    float md[3]; int mi[3];
    int pa = 0, pb = 0;
#pragma unroll
    for (int k = 0; k < 3; ++k) {
      float da = A[pa], db = Bv[pb];
      int ia = I[pa], ib = J[pb];
      bool ta = (da < db) || (da == db && ia < ib);
      md[k] = ta ? da : db; mi[k] = ta ? ia : ib;
      pa += ta ? 1 : 0; pb += ta ? 0 : 1;
    }
    d0 = md[0]; d1 = md[1]; d2 = md[2];
    i0 = mi[0]; i1 = mi[1]; i2 = mi[2];
  }
  if (sub == 0) {
    float w0 = 1.0f / d0, w1 = 1.0f / d1, w2 = 1.0f / d2;
    float s = (w0 + w1) + w2;
    w0 /= s; w1 /= s; w2 /= s;
    const int base = (b * 4096 + n) * 3;
    idxo[base + 0] = i0; idxo[base + 1] = i1; idxo[base + 2] = i2;
    wo[base + 0] = w0; wo[base + 1] = w1; wo[base + 2] = w2;
  }
}

// ---------------- cvt_w: W0 (256x384) ++ W1 (128x256) -> bf16 ----------------
__global__ __launch_bounds__(256) void cvt_w_kernel(
    const float* __restrict__ W0, const float* __restrict__ W1,
    unsigned short* __restrict__ Wb) {
  int i = blockIdx.x * 256 + threadIdx.x;  // 131072 total
  float v = (i < 98304) ? W0[i] : W1[i - 98304];
  Wb[i] = f2bf(v);
}

// ------- tcvt: src fp32 [B][K][N] -> dst bf16 [B][N][K]; grid (N/64, K/64, B) -------
__global__ __launch_bounds__(256) void tcvt_kernel(
    const float* __restrict__ src, unsigned short* __restrict__ dst,
    int K, int N) {
  __shared__ float sm[64][65];
  const int n0 = blockIdx.x * 64, k0 = blockIdx.y * 64, b = blockIdx.z;
  const int tid = threadIdx.x;
  const int nl = tid & 63, kq = tid >> 6;
  const float* s = src + ((size_t)b * K + k0) * N + n0;
#pragma unroll
  for (int p = 0; p < 16; ++p) {
    int kl = p * 4 + kq;
    sm[kl][nl] = s[(size_t)kl * N + nl];
  }
  __syncthreads();
#pragma unroll
  for (int p = 0; p < 2; ++p) {
    int c = p * 256 + tid;
    int rn = c >> 3, jj = c & 7;
    short8 v;
#pragma unroll
    for (int u = 0; u < 8; ++u) v[u] = (short)f2bf(sm[jj * 8 + u][rn]);
    *(short8*)(dst + (size_t)(b * N + n0 + rn) * K + k0 + jj * 8) = v;
  }
}

// ---- interp: interp2[b][n][256] bf16 = sum_k w_k * Xt2[b][idx_k][:] ----
// grid (1024, 16), block 256 = 4 waves, one wave per n, lane = 4 channels
__global__ __launch_bounds__(256) void interp_kernel(
    const unsigned short* __restrict__ Xt2, const int* __restrict__ idx,
    const float* __restrict__ wgt, unsigned short* __restrict__ interp2) {
  const int b = blockIdx.y;
  const int n = blockIdx.x * 4 + (threadIdx.x >> 6);
  const int lane = threadIdx.x & 63;
  const size_t base3 = (size_t)(b * 4096 + n) * 3;
  const int i0 = idx[base3 + 0], i1 = idx[base3 + 1], i2 = idx[base3 + 2];
  const float w0 = wgt[base3 + 0], w1 = wgt[base3 + 1], w2 = wgt[base3 + 2];
  const unsigned short* xb = Xt2 + (size_t)b * 1024 * 256;
  ushort4 a = *(const ushort4*)(xb + (size_t)i0 * 256 + lane * 4);
  ushort4 c = *(const ushort4*)(xb + (size_t)i1 * 256 + lane * 4);
  ushort4 d = *(const ushort4*)(xb + (size_t)i2 * 256 + lane * 4);
  ushort4 o;
  o.x = f2bf(w0 * bf2f(a.x) + w1 * bf2f(c.x) + w2 * bf2f(d.x));
  o.y = f2bf(w0 * bf2f(a.y) + w1 * bf2f(c.y) + w2 * bf2f(d.y));
  o.z = f2bf(w0 * bf2f(a.z) + w1 * bf2f(c.z) + w2 * bf2f(d.z));
  o.w = f2bf(w0 * bf2f(a.w) + w1 * bf2f(c.w) + w2 * bf2f(d.w));
  *(ushort4*)(interp2 + (size_t)(b * 4096 + n) * 256 + lane * 4) = o;
}

// -- gemm0 (+fused stats0): y0t[b][n][256] = W0b * [Xt1 ; interp2] + b0, K=384
//    full o=256, n-tile 64; grid (64, 16) --
__global__ __launch_bounds__(256) void gemm0_kernel(
    const unsigned short* __restrict__ Wb, const unsigned short* __restrict__ Xt1,
    const unsigned short* __restrict__ interp2, const float* __restrict__ b0,
    unsigned short* __restrict__ y0t, float* __restrict__ acc0) {
  __shared__ short sA[256 * 32];   // 256 o-rows x 32 k  (16 KB)
  __shared__ short sB[64 * 32];    // 64 n-rows x 32 k   (4 KB)
  __shared__ float ls[512];        // s[256] | ss[256]
  const int b = blockIdx.y, n0 = blockIdx.x * 64;
  const int tid = threadIdx.x, lane = tid & 63, w = tid >> 6;
  const int quad = lane >> 4, l15 = lane & 15;
  ls[tid] = 0.f; ls[256 + tid] = 0.f;
  floatx4 acc[4][4] = {};   // [o-frag][n-frag]
  for (int kb = 0; kb < 384; kb += 32) {
    __syncthreads();
#pragma unroll
    for (int p = 0; p < 4; ++p) {   // stage W: 256 rows x 32 k
      int c = p * 256 + tid;
      int r = c >> 2, jj = c & 3;
      *(short8*)(sA + c * 8) =
          *(const short8*)(Wb + (size_t)r * 384 + kb + jj * 8);
    }
    {                               // stage X: 64 rows x 32 k from Xt1 or interp2
      int r = tid >> 2, jj = tid & 3;
      const unsigned short* src;
      if (kb < 128)
        src = Xt1 + (size_t)(b * 4096 + n0 + r) * 128 + kb + jj * 8;
      else
        src = interp2 + (size_t)(b * 4096 + n0 + r) * 256 + (kb - 128) + jj * 8;
      *(short8*)(sB + tid * 8) = *(const short8*)src;
    }
    __syncthreads();
    short8 av[4], bv[4];
#pragma unroll
    for (int i = 0; i < 4; ++i)
      av[i] = *(const short8*)(sA + (w * 64 + i * 16 + l15) * 32 + quad * 8);
#pragma unroll
    for (int j = 0; j < 4; ++j)
      bv[j] = *(const short8*)(sB + (j * 16 + l15) * 32 + quad * 8);
#pragma unroll
    for (int i = 0; i < 4; ++i)
#pragma unroll
      for (int j = 0; j < 4; ++j)
        acc[i][j] = __builtin_amdgcn_mfma_f32_16x16x32_bf16(av[i], bv[j], acc[i][j], 0, 0, 0);
  }
#pragma unroll
  for (int i = 0; i < 4; ++i) {
    int obg = w * 64 + i * 16 + quad * 4;   // global o (full 256 per block)
    floatx4 bias = *(const floatx4*)(b0 + obg);
    float ps[4] = {0.f, 0.f, 0.f, 0.f}, pq[4] = {0.f, 0.f, 0.f, 0.f};
#pragma unroll
    for (int j = 0; j < 4; ++j) {
      int n = n0 + j * 16 + l15;
      ushort4 out;
      float v0 = acc[i][j][0] + bias[0];
      float v1 = acc[i][j][1] + bias[1];
      float v2 = acc[i][j][2] + bias[2];
      float v3 = acc[i][j][3] + bias[3];
      out.x = f2bf(v0); out.y = f2bf(v1); out.z = f2bf(v2); out.w = f2bf(v3);
      *(ushort4*)(y0t + (size_t)(b * 4096 + n) * 256 + obg) = out;
      // stats on the ROUNDED values (self-consistent with what gemm1 reads)
      float r0 = bf2f(out.x), r1 = bf2f(out.y), r2 = bf2f(out.z), r3 = bf2f(out.w);
      ps[0] += r0; ps[1] += r1; ps[2] += r2; ps[3] += r3;
      pq[0] += r0 * r0; pq[1] += r1 * r1; pq[2] += r2 * r2; pq[3] += r3 * r3;
    }
#pragma unroll
    for (int u = 0; u < 4; ++u) {
      atomicAdd(&ls[obg + u], ps[u]);
      atomicAdd(&ls[256 + obg + u], pq[u]);
    }
  }
  __syncthreads();
  atomicAdd(&acc0[tid], ls[tid]);
  atomicAdd(&acc0[256 + tid], ls[256 + tid]);
}

// finalize0: st0[o] = scale, st0[256+o] = offset  (BN folded: y = x*scale + offset)
__global__ __launch_bounds__(256) void finalize0_kernel(
    const float* __restrict__ acc0, const float* __restrict__ g0,
    const float* __restrict__ be0, float* __restrict__ st0) {
  int o = threadIdx.x;
  const float inv = 1.0f / 65536.0f;
  float mean = acc0[o] * inv;
  float var = acc0[256 + o] * inv - mean * mean;
  float sc = g0[o] / sqrtf(var + BN_EPS);
  st0[o] = sc;
  st0[256 + o] = be0[o] - mean * sc;
}

// ---- gemm1 (BN+ReLU fused on A-load, fused stats1): y1b bf16 = W1b*relu(bn(y0t))^T + b1
//      full o=128 per block; grid (32, 16) ----
__global__ __launch_bounds__(256) void gemm1_kernel(
    const unsigned short* __restrict__ Wb, const unsigned short* __restrict__ y0t,
    const float* __restrict__ st0, const float* __restrict__ b1,
    unsigned short* __restrict__ y1b, float* __restrict__ acc1) {
  __shared__ short sA[128 * 32];   // 128 n-rows x 32 k  (BN+ReLU'd x1)
  __shared__ short sB[128 * 32];   // 128 o-rows x 32 k
  __shared__ float sst[512];       // scale[256] | offset[256]
  __shared__ float ls[256];        // s[128] | ss[128]
  const int b = blockIdx.y, n0 = blockIdx.x * 128;
  const int tid = threadIdx.x, lane = tid & 63, w = tid >> 6;
  const int wm = w & 1, wo2 = w >> 1, quad = lane >> 4, l15 = lane & 15;
  const unsigned short* W1b = Wb + 98304;
  for (int t = tid; t < 512; t += 256) sst[t] = st0[t];
  if (tid < 256) ls[tid] = 0.f;
  floatx4 acc[4][4] = {};
  for (int kb = 0; kb < 256; kb += 32) {
    __syncthreads();
#pragma unroll
    for (int p = 0; p < 2; ++p) {
      int c = p * 256 + tid;
      int r = c >> 2, jj = c & 3;
      short8 raw = *(const short8*)(y0t + (size_t)(b * 4096 + n0 + r) * 256 + kb + jj * 8);
      int kbase = kb + jj * 8;
      short8 v;
#pragma unroll
      for (int u = 0; u < 8; ++u) {
        int k = kbase + u;
        float rr = fmaxf(bf2f((unsigned short)raw[u]) * sst[k] + sst[256 + k], 0.f);
        v[u] = (short)f2bf(rr);
      }
      *(short8*)(sA + c * 8) = v;
    }
#pragma unroll
    for (int p = 0; p < 2; ++p) {
      int c = p * 256 + tid;
      int r = c >> 2, jj = c & 3;
      *(short8*)(sB + c * 8) =
          *(const short8*)(W1b + (size_t)r * 256 + kb + jj * 8);
    }
    __syncthreads();
    short8 av[4], bv[4];
#pragma unroll
    for (int i = 0; i < 4; ++i)
      av[i] = *(const short8*)(sA + (wm * 64 + i * 16 + l15) * 32 + quad * 8);
#pragma unroll
    for (int j = 0; j < 4; ++j)
      bv[j] = *(const short8*)(sB + (wo2 * 64 + j * 16 + l15) * 32 + quad * 8);
#pragma unroll
    for (int i = 0; i < 4; ++i)
#pragma unroll
      for (int j = 0; j < 4; ++j)
        acc[i][j] = __builtin_amdgcn_mfma_f32_16x16x32_bf16(av[i], bv[j], acc[i][j], 0, 0, 0);
  }
#pragma unroll
  for (int j = 0; j < 4; ++j) {
    int o = wo2 * 64 + j * 16 + l15;
    float bias = b1[o];
    float s = 0.f, q = 0.f;
#pragma unroll
    for (int i = 0; i < 4; ++i) {
      int n = n0 + wm * 64 + i * 16 + quad * 4;
      floatx4 v = acc[i][j] + bias;
      ushort4 out;
      out.x = f2bf(v[0]); out.y = f2bf(v[1]); out.z = f2bf(v[2]); out.w = f2bf(v[3]);
      *(ushort4*)(y1b + (size_t)(b * 128 + o) * 4096 + n) = out;
      s += (v[0] + v[1]) + (v[2] + v[3]);
      q += (v[0] * v[0] + v[1] * v[1]) + (v[2] * v[2] + v[3] * v[3]);
    }
    atomicAdd(&ls[o], s);
    atomicAdd(&ls[128 + o], q);
  }
  __syncthreads();
  if (tid < 128) {
    atomicAdd(&acc1[tid], ls[tid]);
    atomicAdd(&acc1[128 + tid], ls[128 + tid]);
  }
}

__global__ __launch_bounds__(128) void finalize1_kernel(
    const float* __restrict__ acc1, const float* __restrict__ g1,
    float* __restrict__ st1) {
  int o = threadIdx.x;
  const float inv = 1.0f / 65536.0f;
  float mean = acc1[o] * inv;
  float var = acc1[128 + o] * inv - mean * mean;
  st1[o] = mean;
  st1[128 + o] = g1[o] / sqrtf(var + BN_EPS);
}

// -------- bnrelu_b: y1b bf16 -> BN+ReLU -> d_out fp32, ushort4->float4 --------
// grid 8192 x 256  (2,097,152 ushort4 = 8,388,608 elements)
__global__ __launch_bounds__(256) void bnrelu_b_kernel(
    const unsigned short* __restrict__ y1b, const float* __restrict__ st,
    const float* __restrict__ be, float* __restrict__ out) {
  size_t i4 = (size_t)blockIdx.x * 256 + threadIdx.x;  // ushort4 index
  int o = (int)((i4 * 4) >> 12) & 127;
  float m = st[o], sc = st[128 + o], bb = be[o];
  ushort4 v = ((const ushort4*)y1b)[i4];
  floatx4 r;
  r[0] = fmaxf((bf2f(v.x) - m) * sc + bb, 0.f);
  r[1] = fmaxf((bf2f(v.y) - m) * sc + bb, 0.f);
  r[2] = fmaxf((bf2f(v.z) - m) * sc + bb, 0.f);
  r[3] = fmaxf((bf2f(v.w) - m) * sc + bb, 0.f);
  ((floatx4*)out)[i4] = r;
}

extern "C" void kernel_launch(void* const* d_in, const int* in_sizes, int n_in,
                              void* d_out, int out_size, void* d_ws, size_t ws_size,
                              hipStream_t stream) {
  (void)in_sizes; (void)n_in; (void)out_size; (void)ws_size;
  const float* xyz1    = (const float*)d_in[0];
  const float* xyz2    = (const float*)d_in[1];
  const float* points1 = (const float*)d_in[2];
  const float* points2 = (const float*)d_in[3];
  const float* W0  = (const float*)d_in[4];
  const float* b0  = (const float*)d_in[5];
  const float* g0  = (const float*)d_in[6];
  const float* be0 = (const float*)d_in[7];
  const float* W1  = (const float*)d_in[8];
  const float* b1  = (const float*)d_in[9];
  const float* g1  = (const float*)d_in[10];
  const float* be1 = (const float*)d_in[11];

  char* ws = (char*)d_ws;
  // layout (bytes), ~58 MB total:
  //   [0,        768K)   idx  int  (B,N1,3)
  //   [768K,     1.5M)   wgt  f32  (B,N1,3)
  //   [1572864,  +2K)    st0  f32[512]  (scale|offset)
  //   [1574912,  +1K)    st1  f32[256]
  //   [1576960,  +2K)    acc0 f32[512]   } zeroed by one 3072B memset
  //   [1579008,  +1K)    acc1 f32[256]   }
  //   [1581056,  +256K)  Wb   bf16 (W0b 98304 ++ W1b 32768)
  //   [2M,       10M)    Xt2  bf16 (B,1024,256)
  //   [10M,      26M)    Xt1  bf16 (B,4096,128)  -- dead after gemm0; y1b aliases it
  //   [26M,      58M)    y0t  bf16 (B,4096,256)  -- raw pre-BN (BN fused into gemm1)
  // interp2 bf16 (B,4096,256) = 33,554,432 B lives in d_out (exact fit);
  // dead after gemm0, long before bnrelu_b writes d_out.
  int*   idx  = (int*)(ws + 0);
  float* wgt  = (float*)(ws + 786432);
  float* st0  = (float*)(ws + 1572864);
  float* st1  = (float*)(ws + 1574912);
  float* acc0 = (float*)(ws + 1576960);
  float* acc1 = (float*)(ws + 1579008);
  unsigned short* Wb  = (unsigned short*)(ws + 1581056);
  unsigned short* Xt2 = (unsigned short*)(ws + 2097152);
  unsigned short* Xt1 = (unsigned short*)(ws + 10485760);
  unsigned short* y0t = (unsigned short*)(ws + 27262976);
  unsigned short* y1b = (unsigned short*)(ws + 10485760);  // aliases Xt1 (dead)
  unsigned short* interp2 = (unsigned short*)d_out;

  hipMemsetAsync(acc0, 0, 3072, stream);
  cvt_w_kernel<<<512, 256, 0, stream>>>(W0, W1, Wb);
  knn_kernel<<<dim3(128, 16), 256, 0, stream>>>(xyz1, xyz2, idx, wgt);
  tcvt_kernel<<<dim3(16, 4, 16), 256, 0, stream>>>(points2, Xt2, 256, 1024);
  tcvt_kernel<<<dim3(64, 2, 16), 256, 0, stream>>>(points1, Xt1, 128, 4096);
  interp_kernel<<<dim3(1024, 16), 256, 0, stream>>>(Xt2, idx, wgt, interp2);
  gemm0_kernel<<<dim3(64, 16), 256, 0, stream>>>(Wb, Xt1, interp2, b0, y0t, acc0);
  finalize0_kernel<<<1, 256, 0, stream>>>(acc0, g0, be0, st0);
  gemm1_kernel<<<dim3(32, 16), 256, 0, stream>>>(Wb, y0t, st0, b1, y1b, acc1);
  finalize1_kernel<<<1, 128, 0, stream>>>(acc1, g1, st1);
  bnrelu_b_kernel<<<8192, 256, 0, stream>>>(y1b, st1, be1, (float*)d_out);
}